// Round 6
// baseline (1823.187 us; speedup 1.0000x reference)
//
#include <hip/hip_runtime.h>
#include <hip/hip_fp16.h>

#define T_LEN 1024
#define E_DIM 300
#define H_DIM 512
#define D_DIM 1024
#define K_TAGS 12
#define G4 2048   // 4*H

typedef __attribute__((ext_vector_type(8))) short short8x;  // 8 bf16
typedef __attribute__((ext_vector_type(4))) float f32x4;

static __device__ __forceinline__ float frcp(float x){ return __builtin_amdgcn_rcpf(x); }
static __device__ __forceinline__ float sigm(float x){ return frcp(1.f + __expf(-x)); }
// overflow-safe fast tanh
static __device__ __forceinline__ float ftanh(float x){
  const float e = __expf(2.f * fabsf(x));
  const float t = 1.f - 2.f * frcp(e + 1.f);
  return copysignf(t, x);
}
// f32 -> bf16 round-to-nearest-even
static __device__ __forceinline__ unsigned short f2b(float f){
  unsigned u = __float_as_uint(f);
  return (unsigned short)((u + 0x7fffu + ((u >> 16) & 1u)) >> 16);
}
static __device__ __forceinline__ uint4 pack8(const float* s){
  uint4 o;
  o.x = (unsigned)f2b(s[0]) | ((unsigned)f2b(s[1]) << 16);
  o.y = (unsigned)f2b(s[2]) | ((unsigned)f2b(s[3]) << 16);
  o.z = (unsigned)f2b(s[4]) | ((unsigned)f2b(s[5]) << 16);
  o.w = (unsigned)f2b(s[6]) | ((unsigned)f2b(s[7]) << 16);
  return o;
}
static __device__ __forceinline__ uint4 pack8u(const unsigned short* s){
  uint4 o;
  o.x = (unsigned)s[0] | ((unsigned)s[1] << 16);
  o.y = (unsigned)s[2] | ((unsigned)s[3] << 16);
  o.z = (unsigned)s[4] | ((unsigned)s[5] << 16);
  o.w = (unsigned)s[6] | ((unsigned)s[7] << 16);
  return o;
}

// ---------------- gather: xh[t,e] = bf16(word_embeds[sentence[t], e]) ---------
__global__ void k_gather(const int* __restrict__ sent, const float* __restrict__ we,
                         unsigned short* __restrict__ xh){
  int idx = blockIdx.x*256 + threadIdx.x;
  if (idx < T_LEN*E_DIM){
    int t = idx / E_DIM, e = idx - t*E_DIM;
    xh[idx] = f2b(we[(size_t)sent[t]*E_DIM + e]);
  }
}

// ---------------- generic vectorized f32 -> bf16 cast (n multiple of 4) -------
__global__ __launch_bounds__(256) void k_cast(const float* __restrict__ src,
                                              unsigned short* __restrict__ dst,
                                              int n4){
  int i = blockIdx.x*256 + threadIdx.x;
  if (i < n4){
    const float4 v = *reinterpret_cast<const float4*>(src + (size_t)i*4);
    ushort2 a, b;
    a.x = f2b(v.x); a.y = f2b(v.y); b.x = f2b(v.z); b.y = f2b(v.w);
    *reinterpret_cast<ushort2*>(dst + (size_t)i*4)     = a;
    *reinterpret_cast<ushort2*>(dst + (size_t)i*4 + 2) = b;
  }
}

// ------- zero h ring buffer (2048 u32) + xg ready counters (32 u32) -----------
__global__ void k_init(unsigned* __restrict__ hbuf, unsigned* __restrict__ rdy){
  int i = blockIdx.x*256 + threadIdx.x;
  if (i < 2048) hbuf[i] = 0u;  // tag 0, bf16 value +0.0
  if (i < 32)   rdy[i]  = 0u;
}

// ---------------- MFMA bf16 GEMM: C = act( A * B^T + bias ) -------------------
// (pure-bf16 operands, verified round 5; used post-lstm only now)
__global__ __launch_bounds__(256) void k_gemm_mfma(
    const unsigned short* __restrict__ Ah, int lda,
    const unsigned short* __restrict__ Bh, int ldb,
    const float* __restrict__ bias, int act,
    void* __restrict__ Cp, int ldc, int cbf16, int M, int N, int K)
{
  __shared__ __align__(16) unsigned short As[64*40];
  __shared__ __align__(16) unsigned short Bs[64*40];
  const int tid = threadIdx.x;
  const int bm = blockIdx.y*64, bn = blockIdx.x*64;
  const int r  = tid >> 2, c8 = (tid & 3) * 8;
  const int wave = tid >> 6, lane = tid & 63;
  const int wm = (wave >> 1) * 32, wn = (wave & 1) * 32;
  const int col = lane & 15, quad = lane >> 4;

  const unsigned short* arow = Ah + (size_t)(bm+r)*lda;
  const unsigned short* brow = Bh + (size_t)(bn+r)*ldb;

  uint4* aw = (uint4*)(As + r*40 + c8);
  uint4* bw = (uint4*)(Bs + r*40 + c8);

  f32x4 acc[2][2];
  #pragma unroll
  for (int i=0;i<2;i++)
    #pragma unroll
    for (int j=0;j<2;j++) acc[i][j] = (f32x4){0.f,0.f,0.f,0.f};

  for (int k0 = 0; k0 < K; k0 += 32){
    uint4 avv, bvv;
    if (k0 + 32 <= K){
      avv = *(const uint4*)(arow + k0 + c8);
      bvv = *(const uint4*)(brow + k0 + c8);
    } else {
      unsigned short ta[8], tb[8];
      #pragma unroll
      for (int i=0;i<8;i++){
        const int kk = k0 + c8 + i;
        ta[i] = (kk < K) ? arow[kk] : (unsigned short)0;
        tb[i] = (kk < K) ? brow[kk] : (unsigned short)0;
      }
      avv = pack8u(ta); bvv = pack8u(tb);
    }
    if (k0) __syncthreads();
    *aw = avv; *bw = bvv;
    __syncthreads();
    const short8x a0 = *(const short8x*)(As + (wm+col)*40    + quad*8);
    const short8x a1 = *(const short8x*)(As + (wm+16+col)*40 + quad*8);
    const short8x b0 = *(const short8x*)(Bs + (wn+col)*40    + quad*8);
    const short8x b1 = *(const short8x*)(Bs + (wn+16+col)*40 + quad*8);
    acc[0][0] = __builtin_amdgcn_mfma_f32_16x16x32_bf16(a0, b0, acc[0][0], 0, 0, 0);
    acc[0][1] = __builtin_amdgcn_mfma_f32_16x16x32_bf16(a0, b1, acc[0][1], 0, 0, 0);
    acc[1][0] = __builtin_amdgcn_mfma_f32_16x16x32_bf16(a1, b0, acc[1][0], 0, 0, 0);
    acc[1][1] = __builtin_amdgcn_mfma_f32_16x16x32_bf16(a1, b1, acc[1][1], 0, 0, 0);
  }

  #pragma unroll
  for (int mt=0;mt<2;mt++){
    #pragma unroll
    for (int nt=0;nt<2;nt++){
      const int cc = bn + wn + 16*nt + col;
      const float bs = bias ? bias[cc] : 0.f;
      #pragma unroll
      for (int i=0;i<4;i++){
        const int rr = bm + wm + 16*mt + quad*4 + i;
        float v = acc[mt][nt][i] + bs;
        if (act) v = ftanh(v);
        if (cbf16) ((unsigned short*)Cp)[(size_t)rr*ldc + cc] = f2b(v);
        else       ((float*)Cp)[(size_t)rr*ldc + cc] = v;
      }
    }
  }
}

// ---------------- fused: persistent LSTM (blocks 0-63) + xg producers ---------
// Grid = 256 blocks = 1/CU (in-order dispatch -> all 64 lstm WGs co-resident,
// producers never share a CU with an lstm WG).
// lstm path: EXACT verified structure (1340-1410 us band) + a readiness gate on
// its xg loads (RELAXED spin + one ACQUIRE per 64-row block, 16 total; after
// ~t=120 the producer is long done and the gate is a single cached compare).
// producer path: 192 blocks sweep 1024 tile-jobs of the two xg GEMMs
// (row-block 0 of both dirs first); per job: stores -> __syncthreads (drains
// vmcnt) -> one RELEASE agent atomicAdd on xgReady[dir*16+bm].
__global__ __launch_bounds__(256, 1) void k_lstm_fused(
    const float* __restrict__ Whh_f, const float* __restrict__ Whh_b,
    const float* __restrict__ bih_f, const float* __restrict__ bhh_f,
    const float* __restrict__ bih_b, const float* __restrict__ bhh_b,
    float* __restrict__ xg_f, float* __restrict__ xg_b,
    const unsigned short* __restrict__ xh,
    const unsigned short* __restrict__ Wih_fh, const unsigned short* __restrict__ Wih_bh,
    unsigned* __restrict__ hbuf, unsigned* __restrict__ xgReady,
    float* __restrict__ enc)
{
  __shared__ __align__(16) unsigned short As[64*40];
  __shared__ __align__(16) unsigned short Bs[64*40];
  __shared__ __align__(16) unsigned short lds_hb[512];  // h_{t-1} as bf16
  __shared__ __align__(16) float raw[64];               // gate pre-activations

  const int tid = threadIdx.x;
  const int wave = tid >> 6, lane = tid & 63;
  const int col = lane & 15, quad = lane >> 4;

  if (blockIdx.x >= 64){
    // ================= xg producer =================
    const int pid = blockIdx.x - 64;     // 0..191
    const int r  = tid >> 2, c8 = (tid & 3) * 8;
    const int wm = (wave >> 1) * 32, wn = (wave & 1) * 32;
    uint4* aw = (uint4*)(As + r*40 + c8);
    uint4* bw = (uint4*)(Bs + r*40 + c8);

    for (int j = pid; j < 1024; j += 192){
      const int bm = j >> 6, rem = j & 63, pdir = rem >> 5, bn = rem & 31;
      const unsigned short* Bh = pdir ? Wih_bh : Wih_fh;
      float* C = pdir ? xg_b : xg_f;
      const int am = pdir ? (1023 - (bm*64 + r)) : (bm*64 + r);
      const unsigned short* arow = xh + (size_t)am*E_DIM;
      const unsigned short* brow = Bh + (size_t)(bn*64 + r)*E_DIM;

      f32x4 acc[2][2];
      #pragma unroll
      for (int i=0;i<2;i++)
        #pragma unroll
        for (int jj=0;jj<2;jj++) acc[i][jj] = (f32x4){0.f,0.f,0.f,0.f};

      for (int k0 = 0; k0 < E_DIM; k0 += 32){
        uint4 avv, bvv;
        if (k0 + 32 <= E_DIM){
          avv = *(const uint4*)(arow + k0 + c8);
          bvv = *(const uint4*)(brow + k0 + c8);
        } else {
          unsigned short ta[8], tb[8];
          #pragma unroll
          for (int i=0;i<8;i++){
            const int kk = k0 + c8 + i;
            ta[i] = (kk < E_DIM) ? arow[kk] : (unsigned short)0;
            tb[i] = (kk < E_DIM) ? brow[kk] : (unsigned short)0;
          }
          avv = pack8u(ta); bvv = pack8u(tb);
        }
        __syncthreads();           // also protects LDS reuse across jobs
        *aw = avv; *bw = bvv;
        __syncthreads();
        const short8x a0 = *(const short8x*)(As + (wm+col)*40    + quad*8);
        const short8x a1 = *(const short8x*)(As + (wm+16+col)*40 + quad*8);
        const short8x b0 = *(const short8x*)(Bs + (wn+col)*40    + quad*8);
        const short8x b1 = *(const short8x*)(Bs + (wn+16+col)*40 + quad*8);
        acc[0][0] = __builtin_amdgcn_mfma_f32_16x16x32_bf16(a0, b0, acc[0][0], 0, 0, 0);
        acc[0][1] = __builtin_amdgcn_mfma_f32_16x16x32_bf16(a0, b1, acc[0][1], 0, 0, 0);
        acc[1][0] = __builtin_amdgcn_mfma_f32_16x16x32_bf16(a1, b0, acc[1][0], 0, 0, 0);
        acc[1][1] = __builtin_amdgcn_mfma_f32_16x16x32_bf16(a1, b1, acc[1][1], 0, 0, 0);
      }
      #pragma unroll
      for (int mt=0;mt<2;mt++)
        #pragma unroll
        for (int nt=0;nt<2;nt++)
          #pragma unroll
          for (int i=0;i<4;i++)
            C[(size_t)(bm*64 + wm + 16*mt + quad*4 + i)*G4 + (bn*64 + wn + 16*nt + col)]
              = acc[mt][nt][i];
      __syncthreads();  // all threads' stores issued+drained (vmcnt0 before barrier)
      if (tid == 0)
        __hip_atomic_fetch_add(&xgReady[pdir*16 + bm], 1u,
                               __ATOMIC_RELEASE, __HIP_MEMORY_SCOPE_AGENT);
    }
    return;
  }

  // ================= lstm (verified structure) =================
  const int dir = blockIdx.x >> 5;
  const int w   = blockIdx.x & 31;

  const float* Whh = dir ? Whh_b : Whh_f;
  const float* xg  = dir ? xg_b  : xg_f;
  unsigned* rdy = xgReady + dir*16;

  // ---- A-frag preload: wave 'wave' = gate, rows rowA = gate*512 + w*16 + col
  const int rowA = wave*H_DIM + w*16 + col;
  short8x w_frag[16];
  #pragma unroll
  for (int s=0;s<16;s++){
    const float* bp = Whh + (size_t)rowA*H_DIM + s*32 + quad*8;
    uint4 u = pack8(bp);
    w_frag[s] = *reinterpret_cast<short8x*>(&u);
  }

  // ---- wave-0 per-gate-value state (tid<64): bias, xg pipeline
  float bias_r = 0.f, xg_cur = 0.f, c_reg = 0.f;
  int row2 = 0, readyBlk = 0;
  if (tid < 64){
    row2 = (tid >> 4)*H_DIM + w*16 + (tid & 15);
    bias_r = dir ? (bih_b[row2] + bhh_b[row2]) : (bih_f[row2] + bhh_f[row2]);
    // gate row-block 0, then load xg row 0 (step t=1)
    while (__hip_atomic_load(rdy, __ATOMIC_RELAXED, __HIP_MEMORY_SCOPE_AGENT) != 32u) {}
    (void)__hip_atomic_load(rdy, __ATOMIC_ACQUIRE, __HIP_MEMORY_SCOPE_AGENT);
    readyBlk = 1;
    xg_cur = xg[row2];
  }

  unsigned* hb = hbuf + dir*1024;  // [2][512]

  for (int t = 1; t <= T_LEN; ++t){
    // ---- stage h_{t-1}: poll 2 tagged words/thread, mask bf16 into LDS
    {
      unsigned* s0 = hb + ((t-1)&1)*512 + tid;
      const unsigned want = (unsigned)(t-1);
      unsigned v0 = __hip_atomic_load(s0,     __ATOMIC_RELAXED, __HIP_MEMORY_SCOPE_AGENT);
      unsigned v1 = __hip_atomic_load(s0+256, __ATOMIC_RELAXED, __HIP_MEMORY_SCOPE_AGENT);
      while (((v0 >> 16) != want) || ((v1 >> 16) != want)){
        v0 = __hip_atomic_load(s0,     __ATOMIC_RELAXED, __HIP_MEMORY_SCOPE_AGENT);
        v1 = __hip_atomic_load(s0+256, __ATOMIC_RELAXED, __HIP_MEMORY_SCOPE_AGENT);
      }
      lds_hb[tid]     = (unsigned short)(v0 & 0xffffu);
      lds_hb[tid+256] = (unsigned short)(v1 & 0xffffu);
    }
    __syncthreads();

    // prefetch next step's xg (consumed next iteration), gated on readiness
    float xg_nxt = 0.f;
    if (tid < 64 && t < T_LEN){
      const int nb = t >> 6;
      if (nb >= readyBlk){
        while (__hip_atomic_load(rdy + nb, __ATOMIC_RELAXED, __HIP_MEMORY_SCOPE_AGENT) != 32u) {}
        (void)__hip_atomic_load(rdy + nb, __ATOMIC_ACQUIRE, __HIP_MEMORY_SCOPE_AGENT);
        readyBlk = nb + 1;
      }
      xg_nxt = xg[(size_t)t*G4 + row2];
    }

    // ---- matvec: 16 chained-by-2 MFMAs, B = h broadcast-replicated
    f32x4 a0 = (f32x4){0.f,0.f,0.f,0.f}, a1 = (f32x4){0.f,0.f,0.f,0.f};
    #pragma unroll
    for (int s=0;s<16;s+=2){
      const short8x b0 = *(const short8x*)(lds_hb + s*32     + quad*8);
      const short8x b1 = *(const short8x*)(lds_hb + (s+1)*32 + quad*8);
      a0 = __builtin_amdgcn_mfma_f32_16x16x32_bf16(w_frag[s],   b0, a0, 0, 0, 0);
      a1 = __builtin_amdgcn_mfma_f32_16x16x32_bf16(w_frag[s+1], b1, a1, 0, 0, 0);
    }
    if (col == 0){
      f32x4 asum = a0 + a1;   // D[m] in regs i: m = quad*4+i (same for all cols)
      *reinterpret_cast<f32x4*>(raw + wave*16 + quad*4) = asum;
    }
    __syncthreads();

    // ---- gates + state update, all inside wave 0 (shfl handoff, no barrier)
    if (tid < 64){
      float v = raw[tid] + bias_r + xg_cur;
      const float va = ((tid >> 4) == 2) ? ftanh(v) : sigm(v);
      const int l2 = tid & 15;
      const float iv = __shfl(va, l2);
      const float fv = __shfl(va, l2 + 16);
      const float gg = __shfl(va, l2 + 32);
      const float ov = __shfl(va, l2 + 48);
      if (tid < 16){
        c_reg = fv*c_reg + iv*gg;
        const float hh = ov*ftanh(c_reg);
        const int hj = w*16 + tid;
        // publish FIRST (what other WGs wait on) — bf16 payload
        const unsigned hv = ((unsigned)t << 16) | (unsigned)f2b(hh);
        __hip_atomic_store(hb + (t&1)*512 + hj, hv,
                           __ATOMIC_RELAXED, __HIP_MEMORY_SCOPE_AGENT);
        const int tt = dir ? (T_LEN - t) : (t - 1);
        enc[(size_t)tt*D_DIM + dir*H_DIM + hj] = hh;
      }
      xg_cur = xg_nxt;
    }
    __syncthreads();  // protect lds_hb / raw reuse next iteration
  }
}

// ---------------- row softmax in place + bf16 copy, rows of 1024 --------------
__global__ __launch_bounds__(256) void k_softmax(float* __restrict__ S,
                                                 unsigned short* __restrict__ Sh){
  float* r = S + (size_t)blockIdx.x*1024;
  unsigned short* rh = Sh + (size_t)blockIdx.x*1024;
  const int tid = threadIdx.x;
  float v[4];
  #pragma unroll
  for (int i=0;i<4;i++) v[i] = r[tid + i*256];
  float m = fmaxf(fmaxf(v[0],v[1]), fmaxf(v[2],v[3]));
  #pragma unroll
  for (int off=32; off>=1; off>>=1) m = fmaxf(m, __shfl_xor(m, off));
  __shared__ float red[4], red2[4];
  const int wid = tid >> 6, lane = tid & 63;
  if (lane == 0) red[wid] = m;
  __syncthreads();
  m = fmaxf(fmaxf(red[0],red[1]), fmaxf(red[2],red[3]));
  float s = 0.f;
  #pragma unroll
  for (int i=0;i<4;i++){ v[i] = __expf(v[i]-m); s += v[i]; }
  #pragma unroll
  for (int off=32; off>=1; off>>=1) s += __shfl_xor(s, off);
  if (lane == 0) red2[wid] = s;
  __syncthreads();
  s = red2[0]+red2[1]+red2[2]+red2[3];
  const float inv = frcp(s);
  #pragma unroll
  for (int i=0;i<4;i++){
    const float o = v[i]*inv;
    r[tid + i*256]  = o;
    rh[tid + i*256] = f2b(o);
  }
}

// ------- fused enc prep: cath[:, :1024] = bf16(enc); encT = bf16(enc^T) -------
__global__ __launch_bounds__(256) void k_encprep(const float* __restrict__ src,
                                                 unsigned short* __restrict__ cath,
                                                 unsigned short* __restrict__ encT){
  __shared__ float tile[32][33];
  const int bx = blockIdx.x*32, by = blockIdx.y*32;
  const int tx = threadIdx.x & 31, ty8 = threadIdx.x >> 5;
  #pragma unroll
  for (int i=ty8;i<32;i+=8){
    const float v = src[(size_t)(by+i)*1024 + bx+tx];
    tile[i][tx] = v;
    cath[(size_t)(by+i)*2048 + bx+tx] = f2b(v);
  }
  __syncthreads();
  #pragma unroll
  for (int i=ty8;i<32;i+=8) encT[(size_t)(bx+i)*1024 + by+tx] = f2b(tile[tx][i]);
}

// ---------------- feats = h1 * tag_W^T + tag_b  [1024,12] ---------------------
__global__ __launch_bounds__(256) void k_feats(
    const float* __restrict__ h1, const float* __restrict__ tagW,
    const float* __restrict__ tagb, float* __restrict__ feats)
{
  const int t = blockIdx.x;
  const int wave = threadIdx.x >> 6, lane = threadIdx.x & 63;
  const float* hr = h1 + (size_t)t*D_DIM;
  float hv[16];
  #pragma unroll
  for (int i=0;i<16;i++) hv[i] = hr[lane + 64*i];
  #pragma unroll
  for (int j=0;j<3;j++){
    const int tag = wave*3 + j;
    const float* wr = tagW + (size_t)tag*D_DIM;
    float s = 0.f;
    #pragma unroll
    for (int i=0;i<16;i++) s += hv[i]*wr[lane + 64*i];
    #pragma unroll
    for (int off=32; off>=1; off>>=1) s += __shfl_xor(s, off);
    if (lane == 0) feats[(size_t)t*K_TAGS + tag] = s + tagb[tag];
  }
}

// ---------------- CRF phase 1: 64 chunk products in the (LSE,+) semiring ------
__global__ __launch_bounds__(64) void k_crf1(const float* __restrict__ feats,
                                             const float* __restrict__ trans,
                                             float* __restrict__ chunkM){
  const int c = blockIdx.x;      // 0..63
  const int r = threadIdx.x;     // lane; active r<12
  __shared__ float sT[144];
  __shared__ float sF[16*12];
  for (int i=r; i<144; i+=64) sT[i] = trans[i];
  const int t0 = c*16;
  for (int i=r; i<192; i+=64) sF[i] = feats[(size_t)t0*K_TAGS + i];
  __syncthreads();
  if (r < 12){
    float m[12], nm[12];
    #pragma unroll
    for (int k=0;k<12;k++) m[k] = sT[k*12 + r] + sF[k];   // A_{t0} column r
    for (int s=1; s<16; ++s){
      #pragma unroll
      for (int i=0;i<12;i++){
        float v[12]; float mx = -1e30f;
        #pragma unroll
        for (int k=0;k<12;k++){ v[k] = sT[i*12+k] + m[k]; mx = fmaxf(mx, v[k]); }
        float ss = 0.f;
        #pragma unroll
        for (int k=0;k<12;k++) ss += __expf(v[k]-mx);
        nm[i] = sF[s*12+i] + mx + __logf(ss);
      }
      #pragma unroll
      for (int i=0;i<12;i++) m[i] = nm[i];
    }
    #pragma unroll
    for (int k=0;k<12;k++) chunkM[c*144 + k*12 + r] = m[k];
  }
}

// ---------------- CRF phase 2: 64-step alpha chain + gold + output ------------
__global__ __launch_bounds__(128) void k_crf2(const float* __restrict__ chunkM,
                                              const float* __restrict__ feats,
                                              const float* __restrict__ trans,
                                              const int* __restrict__ tags,
                                              float* __restrict__ out){
  const int tid = threadIdx.x, wave = tid >> 6, lane = tid & 63;
  __shared__ float sGold;
  float alpha = (lane == 10) ? 0.f : -10000.f;
  if (wave == 1){
    float g = 0.f;
    for (int i = lane; i <= T_LEN; i += 64){
      const int to = (i < T_LEN) ? tags[i]   : 11;        // STOP
      const int fr = (i == 0)    ? 10        : tags[i-1]; // START
      g += trans[to*K_TAGS + fr];
      if (i < T_LEN) g += feats[(size_t)i*K_TAGS + tags[i]];
    }
    #pragma unroll
    for (int off=32; off>=1; off>>=1) g += __shfl_xor(g, off);
    if (lane == 0) sGold = g;
  } else {
    float pf[12];
    #pragma unroll
    for (int k=0;k<12;k++) pf[k] = (lane < 12) ? chunkM[lane*12 + k] : 0.f;
    for (int c=0; c<64; ++c){
      float av[12];
      #pragma unroll
      for (int j=0;j<12;j++) av[j] = __shfl(alpha, j);
      float cur[12];
      #pragma unroll
      for (int k=0;k<12;k++) cur[k] = pf[k];
      if (c+1 < 64){
        #pragma unroll
        for (int k=0;k<12;k++)
          pf[k] = (lane < 12) ? chunkM[(c+1)*144 + lane*12 + k] : 0.f;
      }
      if (lane < 12){
        float v[12]; float mx = -1e30f;
        #pragma unroll
        for (int k=0;k<12;k++){ v[k] = cur[k] + av[k]; mx = fmaxf(mx, v[k]); }
        float ss = 0.f;
        #pragma unroll
        for (int k=0;k<12;k++) ss += __expf(v[k]-mx);
        alpha = mx + __logf(ss);
      }
    }
  }
  __syncthreads();
  if (wave == 0){
    float v = (lane < K_TAGS) ? (alpha + trans[11*K_TAGS + lane]) : -1e30f;
    float m = v;
    #pragma unroll
    for (int off=32; off>=1; off>>=1) m = fmaxf(m, __shfl_xor(m, off));
    float e = (lane < K_TAGS) ? __expf(v - m) : 0.f;
    #pragma unroll
    for (int off=32; off>=1; off>>=1) e += __shfl_xor(e, off);
    if (lane == 0) out[0] = (m + __logf(e)) - sGold;
  }
}

// ------------------------------------------------------------------------------
extern "C" void kernel_launch(void* const* d_in, const int* in_sizes, int n_in,
                              void* d_out, int out_size, void* d_ws, size_t ws_size,
                              hipStream_t stream)
{
  const int*   sentence = (const int*)d_in[0];
  const int*   tags     = (const int*)d_in[1];
  const float* we       = (const float*)d_in[2];
  const float* Wih_f    = (const float*)d_in[3];
  const float* Whh_f    = (const float*)d_in[4];
  const float* bih_f    = (const float*)d_in[5];
  const float* bhh_f    = (const float*)d_in[6];
  const float* Wih_b    = (const float*)d_in[7];
  const float* Whh_b    = (const float*)d_in[8];
  const float* bih_b    = (const float*)d_in[9];
  const float* bhh_b    = (const float*)d_in[10];
  const float* attn_W   = (const float*)d_in[11];
  const float* attn_b   = (const float*)d_in[12];
  const float* h2h1_W   = (const float*)d_in[13];
  const float* h2h1_b   = (const float*)d_in[14];
  const float* tag_W    = (const float*)d_in[15];
  const float* tag_b    = (const float*)d_in[16];
  const float* trans    = (const float*)d_in[17];
  float* out = (float*)d_out;

  // ---- workspace layout: identical 24 MB footprint, lifetime-aliased --------
  float* ws = (float*)d_ws;
  float* R1 = ws;                    // 2097152 f32 (8 MB)
  float* R2 = ws + 2097152;          // 2097152 f32 (8 MB)
  float* R3 = ws + 4194304;          // 1048576 f32 (4 MB)
  float* R4 = ws + 5242880;          // 1048576 f32 (4 MB)
  float* feats = ws + 6291456;       // 12288 f32
  unsigned* hbuf = (unsigned*)(ws + 6303744);  // 2048 u32

  // pre/during-lstm phase
  float* xg_f = R1;                                        // 8 MB f32
  float* xg_b = R2;                                        // 8 MB f32
  float* enc  = R3;                                        // 4 MB f32
  unsigned short* xh      = (unsigned short*)R4;           // 1024*300
  unsigned short* Wih_fh  = (unsigned short*)R4 + 307200;  // 2048*300
  unsigned short* Wih_bh  = (unsigned short*)R4 + 921600;  // 2048*300 (3 MB total)
  unsigned* xgReady = (unsigned*)feats;                    // 32 u32 (feats dead until k_feats)
  // post-lstm phase (xg_f/xg_b/xh/Wih_* dead)
  unsigned short* cath    = (unsigned short*)R1;           // [1024][2048] bf16 (4 MB)
  unsigned short* attn_Wh = (unsigned short*)(R1 + 1048576); // 1024*1024 (2 MB)
  unsigned short* h2h1_Wh = (unsigned short*)R2;           // 1024*2048 (4 MB)
  float* scores = R2 + 1048576;                            // [1024][1024] f32 (4 MB)
  unsigned short* encT    = (unsigned short*)R4;           // [1024][1024] bf16 (2 MB)
  unsigned short* projh   = (unsigned short*)R4 + 1048576; // [1024][1024] bf16 (2 MB)
  unsigned short* scoresh = (unsigned short*)R3;           // 2 MB (enc dead after encprep GEMMs)
  float* h1     = R3;                                      // 4 MB f32 (scoresh dead)
  float* chunkM = R4;                                      // 36 KB (encT dead after step-10 GEMM)

  // 1. gather embeddings -> bf16
  k_gather<<<dim3((T_LEN*E_DIM + 255)/256), dim3(256), 0, stream>>>(sentence, we, xh);
  // 2. init h ring buffer + xg ready counters
  k_init<<<dim3(8), dim3(256), 0, stream>>>(hbuf, xgReady);
  // 3. precast LSTM input weights
  k_cast<<<dim3(600),  dim3(256), 0, stream>>>(Wih_f, Wih_fh, 153600);
  k_cast<<<dim3(600),  dim3(256), 0, stream>>>(Wih_b, Wih_bh, 153600);
  // 4. fused: bidirectional recurrence (blocks 0-63) + xg GEMM producers
  k_lstm_fused<<<dim3(256), dim3(256), 0, stream>>>(Whh_f, Whh_b, bih_f, bhh_f,
      bih_b, bhh_b, xg_f, xg_b, xh, Wih_fh, Wih_bh, hbuf, xgReady, enc);
  // 5. enc prep: cath[:, :1024] = bf16(enc), encT = bf16(enc^T); precast weights
  k_encprep<<<dim3(32,32), dim3(256), 0, stream>>>(enc, cath, encT);
  k_cast<<<dim3(1024), dim3(256), 0, stream>>>(attn_W, attn_Wh, 262144);
  k_cast<<<dim3(2048), dim3(256), 0, stream>>>(h2h1_W, h2h1_Wh, 524288);
  // 6. projh = bf16(enc * attn_W^T + attn_b)
  k_gemm_mfma<<<dim3(16,16), dim3(256), 0, stream>>>(cath, 2048,
      attn_Wh, D_DIM, attn_b, 0, projh, D_DIM, 1, T_LEN, D_DIM, D_DIM);
  // 7. scores = enc * proj^T   (f32)
  k_gemm_mfma<<<dim3(16,16), dim3(256), 0, stream>>>(cath, 2048,
      projh, D_DIM, nullptr, 0, scores, T_LEN, 0, T_LEN, T_LEN, D_DIM);
  // 8. row softmax in place + bf16 copy
  k_softmax<<<dim3(1024), dim3(256), 0, stream>>>(scores, scoresh);
  // 9. cath[:, 1024:] = bf16(w * enc)  via A=scoresh, B=encT
  k_gemm_mfma<<<dim3(16,16), dim3(256), 0, stream>>>(scoresh, T_LEN,
      encT, D_DIM, nullptr, 0, cath + 1024, 2048, 1, T_LEN, D_DIM, T_LEN);
  // 10. h1 = tanh(cat * h2h1_W^T + h2h1_b), K=2048  (f32)
  k_gemm_mfma<<<dim3(16,16), dim3(256), 0, stream>>>(cath, 2048,
      h2h1_Wh, 2048, h2h1_b, 1, h1, D_DIM, 0, T_LEN, D_DIM, 2048);
  // 11. feats = h1 * tag_W^T + tag_b   [1024,12]
  k_feats<<<dim3(1024), dim3(256), 0, stream>>>(h1, tag_W, tag_b, feats);
  // 12. CRF NLL: 64 parallel chunk products, then 64-step chain + gold
  k_crf1<<<dim3(64), dim3(64), 0, stream>>>(feats, trans, chunkM);
  k_crf2<<<dim3(1), dim3(128), 0, stream>>>(chunkM, feats, trans, tags, out);
}